// Round 2
// baseline (142.225 us; speedup 1.0000x reference)
//
#include <hip/hip_runtime.h>

// PolynomialAttn: B=2,H=16,S=2048,D=64, degree=2, eps=1e-4, fp32 in/out.
// v12: L2-traffic cut. v10/v11 both sustained ~18 TB/s of L2->reg fragment
// streams (1.05 GB/launch; every wave privately re-read its e-half K/V
// stream, duplicated within each block) and were latency-bound on L2 queueing
// (MfmaUtil 24% in BOTH 2-wave/SIMD and 4-wave/SIMD configs => not TLP-fixable).
// v12 stages each 16KB K/V tile ONCE per block into LDS via
// global_load_lds (prepass layout is lane-linear => DMA-compatible),
// double-buffered, counted vmcnt(4) + raw s_barrier (no vmcnt(0) drain in
// loop). Staging LDS (32KB) aliases the epilogue buffer (34.5KB) so the
// block still fits 4 blocks/CU. 4 DMA + 8 ds_read_b128 + 8 MFMA per tile
// per wave; no QK/PV skew (V always LDS-resident).

#define S_LEN 2048
#define DH    64
#define BQ    64
#define BK    64
#define EPSTR 68        // epilogue fp32 stride
#define PSTR  65        // prepass V-transpose LDS stride
#define BH_N  32        // B*H
#define PER_BH (S_LEN * DH)   // 131072 elems
#define NT    (S_LEN / BK)    // 32 KV tiles
#define SMEM_BYTES 35328      // max(2*16KB staging, 34816B epilogue + 512B dbuf)

typedef __bf16 bf16x8 __attribute__((ext_vector_type(8)));
typedef __bf16 bf16x2 __attribute__((ext_vector_type(2)));
typedef float  f32x2  __attribute__((ext_vector_type(2)));
typedef float  f32x4  __attribute__((ext_vector_type(4)));
typedef float  f32x16 __attribute__((ext_vector_type(16)));
typedef unsigned int uivec2 __attribute__((ext_vector_type(2)));

__device__ __forceinline__ unsigned short f2bf(float f) {
    union { float f; unsigned int u; } x; x.f = f;
    unsigned int u = x.u;
    return (unsigned short)((u + 0x7fffu + ((u >> 16) & 1u)) >> 16);  // RNE
}

__device__ __forceinline__ unsigned int pack2bf(float lo, float hi) {
#if __has_builtin(__builtin_amdgcn_cvt_pk_bf16_f32)
    bf16x2 p = __builtin_amdgcn_cvt_pk_bf16_f32(lo, hi);
    union { bf16x2 v; unsigned int u; } c; c.v = p;
    return c.u;
#else
    return (unsigned int)f2bf(lo) | ((unsigned int)f2bf(hi) << 16);
#endif
}

__device__ __forceinline__ void pl32swap(unsigned int& a, unsigned int& b) {
#if __has_builtin(__builtin_amdgcn_permlane32_swap)
    uivec2 r = __builtin_amdgcn_permlane32_swap(a, b, false, false);
    a = r[0]; b = r[1];
#else
    asm("v_permlane32_swap_b32 %0, %1" : "+v"(a), "+v"(b));
#endif
}

// DMA 16B/lane global->LDS (lds dest = uniform base + lane*16, linear).
__device__ __forceinline__ void dma16(const void* g, void* l) {
    __builtin_amdgcn_global_load_lds(
        (const __attribute__((address_space(1))) unsigned int*)g,
        (__attribute__((address_space(3))) unsigned int*)l, 16, 0, 0);
}

// ---------------- prepass: K -> fragment-order bf16, V -> V^T fragment-order bf16 ----
// Kf layout (ushorts): [bh][t][e][ks][lane]*8 ; lane(l31,h) holds
//   K[bh][64t + 32e + l31][16ks + 8h + 0..7]
// Vf layout (ushorts): [bh][t][e][ksl][mt][lane]*8 ; lane(l31,h) holds
//   V^T[bh][mt*32 + l31][64t + 32e + 16ksl + 8h + 0..7]
__global__ __launch_bounds__(256)
void prepass_kernel(const float* __restrict__ kg, const float* __restrict__ vg,
                    unsigned short* __restrict__ kfo, unsigned short* __restrict__ vfo)
{
    __shared__ unsigned short Lk[64 * 72];
    __shared__ unsigned short Lv[64 * PSTR];
    const int tid = threadIdx.x;
    const int bh  = blockIdx.y;
    const int t   = blockIdx.x;
    const size_t base = (size_t)bh * PER_BH + (size_t)t * 64 * DH;

    const float4* kf4 = (const float4*)(kg + base);
    const float4* vf4 = (const float4*)(vg + base);
    #pragma unroll
    for (int r = 0; r < 4; ++r) {
        int idx = r * 256 + tid;              // float4 index in 64x64 tile
        int row = idx >> 4, c4 = idx & 15;
        float4 f = kf4[idx];
        ushort4 hh;
        hh.x = f2bf(f.x); hh.y = f2bf(f.y); hh.z = f2bf(f.z); hh.w = f2bf(f.w);
        *(ushort4*)&Lk[row * 72 + c4 * 4] = hh;
        float4 g = vf4[idx];
        unsigned short* pv = &Lv[row * PSTR + c4 * 4];
        pv[0] = f2bf(g.x); pv[1] = f2bf(g.y); pv[2] = f2bf(g.z); pv[3] = f2bf(g.w);
    }
    __syncthreads();

    unsigned short* kout = kfo + (size_t)bh * PER_BH + (size_t)t * 4096;
    #pragma unroll
    for (int r = 0; r < 2; ++r) {
        int pos = r * 256 + tid;
        int lam = pos & 63, rest = pos >> 6;
        int e = rest >> 2, ks = rest & 3;
        int l31 = lam & 31, h = lam >> 5;
        uint4 v = *(const uint4*)&Lk[(e * 32 + l31) * 72 + ks * 16 + h * 8];
        *(uint4*)(kout + (size_t)pos * 8) = v;
    }
    unsigned short* vout = vfo + (size_t)bh * PER_BH + (size_t)t * 4096;
    #pragma unroll
    for (int r = 0; r < 2; ++r) {
        int pos = r * 256 + tid;
        int lam = pos & 63, rest = pos >> 6;
        int e = rest >> 2, ksl = (rest >> 1) & 1, mt = rest & 1;
        int l31 = lam & 31, h = lam >> 5;
        int d  = mt * 32 + l31;
        int j0 = e * 32 + ksl * 16 + h * 8;
        union { unsigned short s[8]; uint4 u; } u;
        #pragma unroll
        for (int jj = 0; jj < 8; ++jj) u.s[jj] = Lv[(j0 + jj) * PSTR + d];
        *(uint4*)(vout + (size_t)pos * 8) = u.u;
    }
}

// ---------------- main kernel: LDS-staged K/V, 2-barrier tiles, counted vmcnt ------
__global__ __launch_bounds__(256, 4)
void poly_attn_main(const float* __restrict__ qg,
                    const unsigned short* __restrict__ kfo,
                    const unsigned short* __restrict__ vfo,
                    float* __restrict__ og)
{
    __shared__ __align__(16) unsigned char smem[SMEM_BYTES];

    const int tid  = threadIdx.x;
    const int lane = tid & 63;
    const int w    = tid >> 6;
    const int sp   = w >> 1;      // strip: Q rows [32sp, 32sp+32)
    const int e    = w & 1;       // j-half of each KV tile
    const int l31  = lane & 31;
    const int h    = lane >> 5;

    // XCD swizzle: id%8 -> XCD; 4 bh per XCD (K+V 2MB working set in its L2)
    const int id = blockIdx.x;
    const int r5 = id & 31;
    const int bh = (r5 & 7) * 4 + (r5 >> 3);
    const int qt = id >> 5;                 // 0..31
    const int q0 = qt * BQ;

    const float* qb = qg + ((size_t)bh * S_LEN + q0) * DH;
    const unsigned short* kt = kfo + (size_t)bh * PER_BH;
    const unsigned short* vt = vfo + (size_t)bh * PER_BH;
    float* ob = og + ((size_t)bh * S_LEN + q0) * DH;

    // DMA source: wave w stages 4KB chunk w of each 16KB tile
    // (w=0,1 -> K halves, w=2,3 -> V halves), 4 x 1KB instrs.
    const unsigned short* gsrc_base =
        (w < 2) ? (kt + (size_t)w * 2048 + (size_t)lane * 8)
                : (vt + (size_t)(w - 2) * 2048 + (size_t)lane * 8);

    // ---- issue DMA for tile 0 into buf0 as early as possible ----
    {
        unsigned char* lb = smem + (size_t)w * 4096;
        #pragma unroll
        for (int i = 0; i < 4; ++i)
            dma16(gsrc_base + i * 512, lb + i * 1024);
    }

    // ---- Q B-fragments: rows 32sp + l31, cols 16ks + 8h + 0..7 ----
    bf16x8 qfrag[4];
    #pragma unroll
    for (int ks = 0; ks < 4; ++ks) {
        const float* qp = qb + (32 * sp + l31) * DH + ks * 16 + h * 8;
        float4 f0 = *(const float4*)qp;
        float4 f1 = *(const float4*)(qp + 4);
        union { unsigned int d[4]; bf16x8 v; } u;
        u.d[0] = pack2bf(f0.x, f0.y);
        u.d[1] = pack2bf(f0.z, f0.w);
        u.d[2] = pack2bf(f1.x, f1.y);
        u.d[3] = pack2bf(f1.z, f1.w);
        qfrag[ks] = u.v;
    }

    f32x16 oacc[2];   // [mt]: O^T[d=mt*32+(r&3)+8(r>>2)+4h][i=l31] j-half partial
    #pragma unroll
    for (int mt = 0; mt < 2; ++mt)
        #pragma unroll
        for (int r = 0; r < 16; ++r) oacc[mt][r] = 0.f;
    f32x2 ds2; ds2[0] = 0.f; ds2[1] = 0.f;

    unsigned int bsv[2][4];   // transformed B-frags (XF -> PV within iter)

#define XF_STAGE()                                                                  \
        _Pragma("unroll")                                                           \
        for (int ksl = 0; ksl < 2; ++ksl) {                                         \
            f32x2 va, vb, vc, vd;                                                   \
            va[0] = acc[8*ksl+0]; va[1] = acc[8*ksl+1];                             \
            vb[0] = acc[8*ksl+2]; vb[1] = acc[8*ksl+3];                             \
            vc[0] = acc[8*ksl+4]; vc[1] = acc[8*ksl+5];                             \
            vd[0] = acc[8*ksl+6]; vd[1] = acc[8*ksl+7];                             \
            va = va * va; vb = vb * vb; vc = vc * vc; vd = vd * vd;                 \
            ds2 += va; ds2 += vb; ds2 += vc; ds2 += vd;                             \
            unsigned int a0 = pack2bf(va[0], va[1]);                                \
            unsigned int a1 = pack2bf(vb[0], vb[1]);                                \
            unsigned int b0 = pack2bf(vc[0], vc[1]);                                \
            unsigned int b1 = pack2bf(vd[0], vd[1]);                                \
            pl32swap(a0, b0);                                                       \
            pl32swap(a1, b1);                                                       \
            bsv[ksl][0] = a0; bsv[ksl][1] = a1;                                     \
            bsv[ksl][2] = b0; bsv[ksl][3] = b1;                                     \
        }

    // STEP(TT, CUR, PF): if PF, stage tile TT+1 into buf CUR^1; compute tile TT
    // from buf CUR. Counted vmcnt(4): the 4 just-issued DMAs stay in flight
    // across the barrier; own tile-TT DMAs are drained.
#define STEP(TT, CUR, PF)                                                           \
    {                                                                               \
        if (PF) {                                                                   \
            const unsigned short* gs_ = gsrc_base + (size_t)((TT) + 1) * 4096;      \
            unsigned char* lb_ = smem + ((CUR) ^ 1) * 16384 + (size_t)w * 4096;     \
            _Pragma("unroll")                                                       \
            for (int i = 0; i < 4; ++i)                                             \
                dma16(gs_ + i * 512, lb_ + i * 1024);                               \
            asm volatile("s_waitcnt vmcnt(4)" ::: "memory");                        \
        } else {                                                                    \
            asm volatile("s_waitcnt vmcnt(0)" ::: "memory");                        \
        }                                                                           \
        __builtin_amdgcn_s_barrier();                                               \
        asm volatile("" ::: "memory");                                              \
        __builtin_amdgcn_sched_barrier(0);                                          \
        const unsigned char* cb_ = smem + (CUR) * 16384;                            \
        const unsigned char* kb_ = cb_ + e * 4096 + (size_t)lane * 16;              \
        uint4 kf0 = *(const uint4*)(kb_);                                           \
        uint4 kf1 = *(const uint4*)(kb_ + 1024);                                    \
        uint4 kf2 = *(const uint4*)(kb_ + 2048);                                    \
        uint4 kf3 = *(const uint4*)(kb_ + 3072);                                    \
        f32x16 acc;                                                                 \
        _Pragma("unroll")                                                           \
        for (int r = 0; r < 16; ++r) acc[r] = 0.f;                                  \
        {                                                                           \
            union { uint4 u; bf16x8 v; } kc;                                        \
            kc.u = kf0; acc = __builtin_amdgcn_mfma_f32_32x32x16_bf16(kc.v, qfrag[0], acc, 0, 0, 0); \
            kc.u = kf1; acc = __builtin_amdgcn_mfma_f32_32x32x16_bf16(kc.v, qfrag[1], acc, 0, 0, 0); \
            kc.u = kf2; acc = __builtin_amdgcn_mfma_f32_32x32x16_bf16(kc.v, qfrag[2], acc, 0, 0, 0); \
            kc.u = kf3; acc = __builtin_amdgcn_mfma_f32_32x32x16_bf16(kc.v, qfrag[3], acc, 0, 0, 0); \
        }                                                                           \
        const unsigned char* vb_ = cb_ + 8192 + e * 4096 + (size_t)lane * 16;       \
        uint4 vf0 = *(const uint4*)(vb_);                                           \
        uint4 vf1 = *(const uint4*)(vb_ + 1024);                                    \
        uint4 vf2 = *(const uint4*)(vb_ + 2048);                                    \
        uint4 vf3 = *(const uint4*)(vb_ + 3072);                                    \
        XF_STAGE();                                                                 \
        _Pragma("unroll")                                                           \
        for (int ksl = 0; ksl < 2; ++ksl) {                                         \
            union { unsigned int d[4]; bf16x8 v; } bu;                              \
            bu.d[0] = bsv[ksl][0]; bu.d[1] = bsv[ksl][1];                           \
            bu.d[2] = bsv[ksl][2]; bu.d[3] = bsv[ksl][3];                           \
            union { uint4 u; bf16x8 v; } vv;                                        \
            vv.u = (ksl == 0 ? vf0 : vf2);                                          \
            oacc[0] = __builtin_amdgcn_mfma_f32_32x32x16_bf16(vv.v, bu.v, oacc[0], 0, 0, 0); \
            vv.u = (ksl == 0 ? vf1 : vf3);                                          \
            oacc[1] = __builtin_amdgcn_mfma_f32_32x32x16_bf16(vv.v, bu.v, oacc[1], 0, 0, 0); \
        }                                                                           \
        __builtin_amdgcn_s_barrier();                                               \
        asm volatile("" ::: "memory");                                              \
    }

    for (int T = 0; T < NT - 2; T += 2) {
        STEP(T,     0, 1);
        STEP(T + 1, 1, 1);
    }
    STEP(NT - 2, 0, 1);
    STEP(NT - 1, 1, 0);
#undef STEP
#undef XF_STAGE

    // ---- denominator partial (column i = l31, this wave's j-half) ----
    float wavetot;
    { float t = ds2[0] + ds2[1]; wavetot = t + __shfl_xor(t, 32); }

    // ---- epilogue: stash partials in (re-aliased) LDS, combine, store ----
    float* epb  = (float*)smem;                 // 4 regions x 32 x EPSTR
    float* dbuf = (float*)(smem + 34816);       // 128 floats
    {
        float* ep = epb + (size_t)w * (32 * EPSTR);
        #pragma unroll
        for (int mt = 0; mt < 2; ++mt) {
            #pragma unroll
            for (int g = 0; g < 4; ++g) {
                f32x4 vv;
                vv[0] = oacc[mt][4*g+0];
                vv[1] = oacc[mt][4*g+1];
                vv[2] = oacc[mt][4*g+2];
                vv[3] = oacc[mt][4*g+3];
                // O[i=l31][d = mt*32 + 8g + 4h + 0..3]
                *(f32x4*)&ep[l31 * EPSTR + mt * 32 + 8 * g + 4 * h] = vv;
            }
        }
        if (h == 0) dbuf[w * 32 + l31] = wavetot;
    }
    __syncthreads();

    // wave w: output strip so = w>>1 (rows [32so,32so+32)), d-half ho = w&1
    const int so = w >> 1, ho = w & 1;
    const int lr = lane >> 1;
    const float den = dbuf[(2 * so + 0) * 32 + lr] + dbuf[(2 * so + 1) * 32 + lr];
    const float inv = 1.0f / fmaxf(den, 1e-4f);
    const float* ea = epb + (size_t)(2 * so + 0) * (32 * EPSTR) + lr * EPSTR;
    const float* eb = epb + (size_t)(2 * so + 1) * (32 * EPSTR) + lr * EPSTR;
    #pragma unroll
    for (int it = 0; it < 4; ++it) {
        int d0 = ho * 32 + (lane & 1) * 16 + it * 4;
        f32x4 a = *(const f32x4*)&ea[d0];
        f32x4 b = *(const f32x4*)&eb[d0];
        f32x4 sm;
        sm[0] = (a[0] + b[0]) * inv;
        sm[1] = (a[1] + b[1]) * inv;
        sm[2] = (a[2] + b[2]) * inv;
        sm[3] = (a[3] + b[3]) * inv;
        *(f32x4*)&ob[(32 * so + lr) * DH + d0] = sm;
    }
}

// ---------------- fallback (self-contained, used if ws too small) ----------------
#define LSTR 72
__global__ __launch_bounds__(256, 2)
void poly_attn_fallback(const float* __restrict__ qg, const float* __restrict__ kg,
                        const float* __restrict__ vg, float* __restrict__ og)
{
    __shared__ unsigned short Qs[64 * LSTR];
    __shared__ unsigned short Ksl[64 * LSTR];
    __shared__ unsigned short Vt[64 * LSTR];
    __shared__ unsigned short Xsl[64 * LSTR];

    const int tid  = threadIdx.x;
    const int lane = tid & 63;
    const int w    = tid >> 6;
    const int c    = lane & 15;
    const int quad = lane >> 4;
    const int i0   = w * 16;

    const int bh = blockIdx.y;
    const int q0 = blockIdx.x * 64;

    const float* qb = qg + ((size_t)bh * S_LEN + q0) * DH;
    const float* kb = kg + (size_t)bh * S_LEN * DH;
    const float* vb = vg + (size_t)bh * S_LEN * DH;
    float*       ob = og + ((size_t)bh * S_LEN + q0) * DH;

    {
        const float4* qf4 = (const float4*)qb;
        #pragma unroll
        for (int r = 0; r < 4; ++r) {
            int idx = r * 256 + tid;
            int row = idx >> 4, c4 = idx & 15;
            float4 f = qf4[idx];
            ushort4 hh;
            hh.x = f2bf(f.x); hh.y = f2bf(f.y); hh.z = f2bf(f.z); hh.w = f2bf(f.w);
            *(ushort4*)&Qs[row * LSTR + c4 * 4] = hh;
        }
    }

    f32x4 oacc[4];
    #pragma unroll
    for (int t = 0; t < 4; ++t) { oacc[t][0]=0.f; oacc[t][1]=0.f; oacc[t][2]=0.f; oacc[t][3]=0.f; }
    float dsum[4] = {0.f, 0.f, 0.f, 0.f};

    for (int t0 = 0; t0 < S_LEN; t0 += 64) {
        __syncthreads();
        {
            const float4* kf4 = (const float4*)(kb + (size_t)t0 * DH);
            const float4* vf4 = (const float4*)(vb + (size_t)t0 * DH);
            #pragma unroll
            for (int r = 0; r < 4; ++r) {
                int idx = r * 256 + tid;
                int row = idx >> 4, c4 = idx & 15;
                float4 f = kf4[idx];
                ushort4 hh;
                hh.x = f2bf(f.x); hh.y = f2bf(f.y); hh.z = f2bf(f.z); hh.w = f2bf(f.w);
                *(ushort4*)&Ksl[row * LSTR + c4 * 4] = hh;
                float4 g = vf4[idx];
                int d0 = c4 * 4;
                Vt[(d0 + 0) * LSTR + row] = f2bf(g.x);
                Vt[(d0 + 1) * LSTR + row] = f2bf(g.y);
                Vt[(d0 + 2) * LSTR + row] = f2bf(g.z);
                Vt[(d0 + 3) * LSTR + row] = f2bf(g.w);
            }
        }
        __syncthreads();

        f32x4 xacc[4];
        #pragma unroll
        for (int t = 0; t < 4; ++t) { xacc[t][0]=0.f; xacc[t][1]=0.f; xacc[t][2]=0.f; xacc[t][3]=0.f; }
        #pragma unroll
        for (int k0 = 0; k0 < 64; k0 += 32) {
            bf16x8 af = *(const bf16x8*)&Qs[(i0 + c) * LSTR + k0 + quad * 8];
            #pragma unroll
            for (int tn = 0; tn < 4; ++tn) {
                bf16x8 bfg = *(const bf16x8*)&Ksl[(tn * 16 + c) * LSTR + k0 + quad * 8];
                xacc[tn] = __builtin_amdgcn_mfma_f32_16x16x32_bf16(af, bfg, xacc[tn], 0, 0, 0);
            }
        }
        #pragma unroll
        for (int tn = 0; tn < 4; ++tn)
            #pragma unroll
            for (int r = 0; r < 4; ++r) {
                float xv = xacc[tn][r];
                float xs = xv * xv;
                dsum[r] += xs;
                Xsl[(i0 + quad * 4 + r) * LSTR + tn * 16 + c] = f2bf(xs);
            }
        __syncthreads();

        #pragma unroll
        for (int k0 = 0; k0 < 64; k0 += 32) {
            bf16x8 af = *(const bf16x8*)&Xsl[(i0 + c) * LSTR + k0 + quad * 8];
            #pragma unroll
            for (int tn = 0; tn < 4; ++tn) {
                bf16x8 bfg = *(const bf16x8*)&Vt[(tn * 16 + c) * LSTR + k0 + quad * 8];
                oacc[tn] = __builtin_amdgcn_mfma_f32_16x16x32_bf16(af, bfg, oacc[tn], 0, 0, 0);
            }
        }
    }

    #pragma unroll
    for (int r = 0; r < 4; ++r) {
        float s = dsum[r];
        s += __shfl_xor(s, 1);
        s += __shfl_xor(s, 2);
        s += __shfl_xor(s, 4);
        s += __shfl_xor(s, 8);
        dsum[r] = 1.0f / fmaxf(s, 1e-4f);
    }
    #pragma unroll
    for (int tn = 0; tn < 4; ++tn)
        #pragma unroll
        for (int r = 0; r < 4; ++r)
            ob[(i0 + quad * 4 + r) * DH + tn * 16 + c] = oacc[tn][r] * dsum[r];
}

extern "C" void kernel_launch(void* const* d_in, const int* in_sizes, int n_in,
                              void* d_out, int out_size, void* d_ws, size_t ws_size,
                              hipStream_t stream) {
    (void)in_sizes; (void)n_in; (void)out_size;
    const float* q = (const float*)d_in[0];
    const float* k = (const float*)d_in[1];
    const float* v = (const float*)d_in[2];
    float* o = (float*)d_out;

    const size_t elems = (size_t)BH_N * PER_BH;              // 4,194,304
    const size_t need  = 2 * elems * sizeof(unsigned short); // 16.78 MB

    if (ws_size >= need) {
        unsigned short* kfo = (unsigned short*)d_ws;
        unsigned short* vfo = kfo + elems;
        prepass_kernel<<<dim3(NT, BH_N), 256, 0, stream>>>(k, v, kfo, vfo);
        poly_attn_main<<<dim3(BH_N * S_LEN / BQ), 256, 0, stream>>>(q, kfo, vfo, o);
    } else {
        poly_attn_fallback<<<dim3(S_LEN / 64, BH_N), 256, 0, stream>>>(q, k, v, o);
    }
}